// Round 2
// baseline (393.895 us; speedup 1.0000x reference)
//
#include <hip/hip_runtime.h>
#include <math.h>

// Problem constants (fixed by setup_inputs):
//   x: (512, 512, 9, 9) fp32, theta: (4,) fp32, lam: (4,) fp32
//   out: (4*512, 512, 9, 9) fp32 = gabor[g,h,w] * x[co,ci,h,w]
#define NG   4
#define HW   81                    // 9*9
#define NELT (512 * 512 * 81)      // elements of x = 21,233,664
#define N4   (NELT / 4)            // float4 count   =  5,308,416
#define BLK  256
#define NBLK 2048                  // persistent-ish: 8 blocks/CU, grid-stride
#define NTHR (NBLK * BLK)          // 524,288 threads -> 10.125 iters each

typedef float v4f __attribute__((ext_vector_type(4)));

__global__ __launch_bounds__(BLK) void gabor_mul_kernel(
    const float* __restrict__ x,
    const float* __restrict__ theta,
    const float* __restrict__ lam,
    float* __restrict__ out)
{
    // Transposed Gabor table: gf4[p] = {g(0,p), g(1,p), g(2,p), g(3,p)}
    __shared__ v4f gf4[HW];

    const float PI_F = 3.14159274101257324f;       // np.float32(np.pi)
    const float INV_2SIG2 = 1.0f / (2.0f * PI_F * PI_F);
    if (threadIdx.x < HW) {
        int p = threadIdx.x;
        int i = p / 9;
        int j = p - i * 9;
        float fy = (float)(i - 4);
        float fx = (float)(j - 4);
        float env = expf(-(fx * fx + fy * fy) * INV_2SIG2);
        v4f v;
#pragma unroll
        for (int g = 0; g < NG; ++g) {
            float th = theta[g];
            float l  = lam[g];
            float xr = fx * cosf(th) + fy * sinf(th);
            v[g] = env * cosf(2.0f * PI_F * xr * l);
        }
        gf4[p] = v;
    }
    __syncthreads();

    const v4f* __restrict__ x4 = (const v4f*)x;
    v4f* out4 = (v4f*)out;

    unsigned gtid = blockIdx.x * BLK + threadIdx.x;
    for (unsigned u = gtid; u < N4; u += NTHR) {
        unsigned base = u * 4u;
        unsigned p0 = base % 81u;                  // magic-mul, no div unit
        unsigned p1 = p0 + 1u; if (p1 >= 81u) p1 -= 81u;
        unsigned p2 = p1 + 1u; if (p2 >= 81u) p2 -= 81u;
        unsigned p3 = p2 + 1u; if (p3 >= 81u) p3 -= 81u;

        const v4f xv = x4[u];
        // one ds_read_b128 per position; mod-81 wrap scatters bank quads
        const v4f g0 = gf4[p0];
        const v4f g1 = gf4[p1];
        const v4f g2 = gf4[p2];
        const v4f g3 = gf4[p3];

#pragma unroll
        for (int g = 0; g < NG; ++g) {
            v4f o;
            o.x = xv.x * g0[g];
            o.y = xv.y * g1[g];
            o.z = xv.z * g2[g];
            o.w = xv.w * g3[g];
            __builtin_nontemporal_store(o, &out4[(size_t)g * (size_t)N4 + (size_t)u]);
        }
    }
}

extern "C" void kernel_launch(void* const* d_in, const int* in_sizes, int n_in,
                              void* d_out, int out_size, void* d_ws, size_t ws_size,
                              hipStream_t stream) {
    const float* x     = (const float*)d_in[0];
    const float* theta = (const float*)d_in[1];
    const float* lam   = (const float*)d_in[2];
    float* out = (float*)d_out;

    gabor_mul_kernel<<<NBLK, BLK, 0, stream>>>(x, theta, lam, out);
}